// Round 5
// baseline (93.063 us; speedup 1.0000x reference)
//
#include <hip/hip_runtime.h>

// ArgumentLocalLogits: BS=16, CTX_PER=1024, ARGS_PER=32, KEY_DIM=128, D_MODEL=512
// rows[p] = p>>10 ; logits[p] = dot(Q[p>>10], keys[(p>>15)*1024 + (p&1023)])
// Restructure: logits = (Q @ W^T) @ ctx^T + Q.b
// ws: Qp bf16 [512][512] + qb f32 [512]
// out: [P floats rows-as-float][P floats logits]

#define BSZ        16
#define CTX_PER    1024
#define ARGS_PER   32
#define KD         128
#define DM         512
#define N_ARGS     (BSZ * ARGS_PER)    // 512
#define P_TOTAL    (N_ARGS * CTX_PER)  // 524288

typedef __attribute__((ext_vector_type(8))) short short8;
typedef __attribute__((ext_vector_type(4))) float float4v;

__device__ inline short bf16_of(float x) {
    unsigned u = __builtin_bit_cast(unsigned, x);
    unsigned r = (u + 0x7fffu + ((u >> 16) & 1u)) >> 16;   // RNE
    return (short)r;
}

__device__ inline short8 cvt8(float4 lo, float4 hi) {
    short8 r;
    r[0] = bf16_of(lo.x); r[1] = bf16_of(lo.y); r[2] = bf16_of(lo.z); r[3] = bf16_of(lo.w);
    r[4] = bf16_of(hi.x); r[5] = bf16_of(hi.y); r[6] = bf16_of(hi.z); r[7] = bf16_of(hi.w);
    return r;
}

// Qp[a][m] = sum_d arg[a][d] * W[m][d]  (bf16), qb[a] = dot(arg[a], b)
// grid 256: mtile = b>>3 (16 args), ntile = (b&7)*4 + wave (16 W-rows). 1 MFMA tile per wave.
__global__ __launch_bounds__(256) void qproj_kernel(
    const float* __restrict__ arg, const float* __restrict__ W,
    const float* __restrict__ b, short* __restrict__ Qp, float* __restrict__ qb)
{
    const int t = threadIdx.x, lane = t & 63, wave = t >> 6;
    const int mtile = blockIdx.x >> 3;
    const int ntile = (blockIdx.x & 7) * 4 + wave;
    const int n = lane & 15, quad = lane >> 4;

    // A[m=arg][k=d]: m = lane&15, k = quad*8+j
    const float* asrc = arg + (size_t)(mtile * 16 + n) * KD + quad * 8;
    short8 afr[4];
    #pragma unroll
    for (int kt = 0; kt < 4; ++kt)
        afr[kt] = cvt8(*(const float4*)(asrc + kt * 32), *(const float4*)(asrc + kt * 32 + 4));

    // B[k=d][n=W-row]: n = lane&15
    const float* wsrc = W + (size_t)(ntile * 16 + n) * KD + quad * 8;
    float4v acc = {0.f, 0.f, 0.f, 0.f};
    #pragma unroll
    for (int kt = 0; kt < 4; ++kt) {
        short8 bfr = cvt8(*(const float4*)(wsrc + kt * 32), *(const float4*)(wsrc + kt * 32 + 4));
        acc = __builtin_amdgcn_mfma_f32_16x16x32_bf16(afr[kt], bfr, acc, 0, 0, 0);
    }
    // D: col = lane&15 (= W row-in-tile), row = quad*4+r (= arg-in-tile)
    #pragma unroll
    for (int r = 0; r < 4; ++r)
        Qp[(size_t)(mtile * 16 + quad * 4 + r) * DM + ntile * 16 + n] = bf16_of(acc[r]);

    // qb: only one n-group per m-tile computes it
    if ((blockIdx.x & 7) == 0) {
        __shared__ float red[16][17];
        const int al = t >> 4, seg = t & 15;
        const float* qrow = arg + (size_t)(mtile * 16 + al) * KD + seg * 8;
        float p = 0.f;
        #pragma unroll
        for (int j = 0; j < 8; ++j) p += qrow[j] * b[seg * 8 + j];
        red[al][seg] = p;
        __syncthreads();
        if (t < 16) {
            float ssum = 0.f;
            #pragma unroll
            for (int j = 0; j < 16; ++j) ssum += red[t][j];
            qb[mtile * 16 + t] = ssum;
        }
    }
}

// grid 512 = 16 states x 32 groups of 32 ctx rows (2 sub-chunks of 16, double-buffered).
// 4 waves split K=512 (128 each); A-fragments (Qp) held in REGISTERS, loaded direct
// from L2-hot Qp at block start. ctx staged via coalesced float4 -> bf16 LDS.
// Partials reduced via small Sp buffer. Fully resident: 2 blocks/CU x 256 CUs = 512.
__global__ __launch_bounds__(256, 2) void main_kernel(
    const float* __restrict__ ctx, const short* __restrict__ Qp,
    const float* __restrict__ qb, float* __restrict__ out)
{
    __shared__ __align__(16) short Cxl[2][16][520];  // 2 x 16640 B, pad 520 -> 2-way (free)
    __shared__ float Sp[4][544];                     // [wave][arg*17+col], 8704 B
    // total LDS = 41984 B

    const int t = threadIdx.x, lane = t & 63, wave = t >> 6;
    const int s = blockIdx.x >> 5;
    const int grp = blockIdx.x & 31;                 // 32-row group
    const int n = lane & 15, quad = lane >> 4;
    const int k0 = wave * 128;                       // this wave's K-slice

    // A-fragments direct from global (L2-hot): Qp[s*32 + mt*16 + n][k0 + kt*32 + quad*8]
    // Each instr: 16 row-segments x 64 B contiguous (quads cover 64 B) -> full sectors.
    short8 afr[2][4];
    {
        const short* qsrc = Qp + (size_t)(s * 32 + n) * DM + k0 + quad * 8;
        #pragma unroll
        for (int mt = 0; mt < 2; ++mt)
            #pragma unroll
            for (int kt = 0; kt < 4; ++kt)
                afr[mt][kt] = *(const short8*)(qsrc + (size_t)mt * 16 * DM + kt * 32);
    }

    // stage ctx sub-chunk 0 (16x512 fp32 -> bf16), coalesced
    const float* cbase = ctx + (size_t)(s * CTX_PER + grp * 32) * DM;
    const int srow = t >> 6, sc8 = t & 63;           // this thread's (row-quarter, col8)
    #pragma unroll
    for (int i = 0; i < 4; ++i) {
        const float* p = cbase + (size_t)(i * 4 + srow) * DM + sc8 * 8;
        *(short8*)&Cxl[0][i * 4 + srow][sc8 * 8] = cvt8(*(const float4*)p, *(const float4*)(p + 4));
    }

    const int a_red = t >> 3;                        // reduce phase: arg row [0,32)
    const int c2 = (t & 7) * 2;                      // reduce phase: col pair
    const int ga = s * ARGS_PER + a_red;
    const float qbv = qb[ga];
    const float2 rowsv = make_float2((float)ga, (float)ga);

    __syncthreads();                                 // B0: Cxl[0] ready

    #pragma unroll
    for (int c = 0; c < 2; ++c) {
        // prefetch sub-chunk 1 while chunk 0 computes
        float4 pf[8];
        if (c == 0) {
            #pragma unroll
            for (int i = 0; i < 4; ++i) {
                const float* p = cbase + (size_t)(16 + i * 4 + srow) * DM + sc8 * 8;
                pf[2 * i]     = *(const float4*)p;
                pf[2 * i + 1] = *(const float4*)(p + 4);
            }
        }

        float4v acc0 = {0.f, 0.f, 0.f, 0.f};
        float4v acc1 = {0.f, 0.f, 0.f, 0.f};
        #pragma unroll
        for (int kt = 0; kt < 4; ++kt) {
            short8 bfr = *(const short8*)&Cxl[c][n][k0 + kt * 32 + quad * 8];
            acc0 = __builtin_amdgcn_mfma_f32_16x16x32_bf16(afr[0][kt], bfr, acc0, 0, 0, 0);
            acc1 = __builtin_amdgcn_mfma_f32_16x16x32_bf16(afr[1][kt], bfr, acc1, 0, 0, 0);
        }

        if (c == 0) {
            #pragma unroll
            for (int i = 0; i < 4; ++i)
                *(short8*)&Cxl[1][i * 4 + srow][sc8 * 8] = cvt8(pf[2 * i], pf[2 * i + 1]);
        }

        // K-split partials -> Sp  (D: col = lane&15 = ctx row, row = quad*4+r = arg)
        #pragma unroll
        for (int r = 0; r < 4; ++r) {
            Sp[wave][(quad * 4 + r) * 17 + n]        = acc0[r];
            Sp[wave][(16 + quad * 4 + r) * 17 + n]   = acc1[r];
        }
        __syncthreads();                             // Sp visible; Cxl[1] complete

        // reduce 4 wave-partials + qb, store logits + rows
        const int base = a_red * 17 + c2;
        float v0 = Sp[0][base]     + Sp[1][base]     + Sp[2][base]     + Sp[3][base];
        float v1 = Sp[0][base + 1] + Sp[1][base + 1] + Sp[2][base + 1] + Sp[3][base + 1];
        const size_t off = (size_t)ga * CTX_PER + grp * 32 + c * 16 + c2;
        *(float2*)(out + P_TOTAL + off) = make_float2(v0 + qbv, v1 + qbv);
        *(float2*)(out + off)           = rowsv;

        if (c == 0) __syncthreads();                 // Sp reads done before next writes
    }
}

extern "C" void kernel_launch(void* const* d_in, const int* in_sizes, int n_in,
                              void* d_out, int out_size, void* d_ws, size_t ws_size,
                              hipStream_t stream)
{
    // setup_inputs order: bs, arg_ids, ctx_ids, arg_values, ctx_values, W, b
    const float* arg_values = (const float*)d_in[3];
    const float* ctx_values = (const float*)d_in[4];
    const float* W          = (const float*)d_in[5];
    const float* b          = (const float*)d_in[6];
    float* out = (float*)d_out;

    short* Qp = (short*)d_ws;
    float* qb = (float*)((char*)d_ws + (size_t)N_ARGS * DM * sizeof(short));

    qproj_kernel<<<256, 256, 0, stream>>>(arg_values, W, b, Qp, qb);
    main_kernel<<<BSZ * 32, 256, 0, stream>>>(ctx_values, Qp, qb, out);
}

// Round 6
// 91.585 us; speedup vs baseline: 1.0161x; 1.0161x over previous
//
#include <hip/hip_runtime.h>

// ArgumentLocalLogits: BS=16, CTX_PER=1024, ARGS_PER=32, KEY_DIM=128, D_MODEL=512
// rows[p] = p>>10 ; logits[p] = dot(Q[p>>10], keys[(p>>15)*1024 + (p&1023)])
// Restructure: logits = (Q @ W^T) @ ctx^T + Q.b
// ws: Qp bf16 [512][512] + qb f32 [512]
// out: [P floats rows-as-float][P floats logits]
//
// R6 = exact revert to R4 (best measured: 91.67 us). R5's register-A-frag +
// double-buffer + 512-block variant regressed to 93.06.

#define BSZ        16
#define CTX_PER    1024
#define ARGS_PER   32
#define KD         128
#define DM         512
#define N_ARGS     (BSZ * ARGS_PER)    // 512
#define P_TOTAL    (N_ARGS * CTX_PER)  // 524288

typedef __attribute__((ext_vector_type(8))) short short8;
typedef __attribute__((ext_vector_type(4))) float float4v;

__device__ inline short bf16_of(float x) {
    unsigned u = __builtin_bit_cast(unsigned, x);
    unsigned r = (u + 0x7fffu + ((u >> 16) & 1u)) >> 16;   // RNE
    return (short)r;
}

__device__ inline short8 cvt8(float4 lo, float4 hi) {
    short8 r;
    r[0] = bf16_of(lo.x); r[1] = bf16_of(lo.y); r[2] = bf16_of(lo.z); r[3] = bf16_of(lo.w);
    r[4] = bf16_of(hi.x); r[5] = bf16_of(hi.y); r[6] = bf16_of(hi.z); r[7] = bf16_of(hi.w);
    return r;
}

// Qp[a][m] = sum_d arg[a][d] * W[m][d]  (bf16), qb[a] = dot(arg[a], b)
// grid 256: mtile = b>>3 (16 args), ntile = (b&7)*4 + wave (16 W-rows). 1 MFMA tile per wave.
__global__ __launch_bounds__(256) void qproj_kernel(
    const float* __restrict__ arg, const float* __restrict__ W,
    const float* __restrict__ b, short* __restrict__ Qp, float* __restrict__ qb)
{
    const int t = threadIdx.x, lane = t & 63, wave = t >> 6;
    const int mtile = blockIdx.x >> 3;
    const int ntile = (blockIdx.x & 7) * 4 + wave;
    const int n = lane & 15, quad = lane >> 4;

    // A[m=arg][k=d]: m = lane&15, k = quad*8+j
    const float* asrc = arg + (size_t)(mtile * 16 + n) * KD + quad * 8;
    short8 afr[4];
    #pragma unroll
    for (int kt = 0; kt < 4; ++kt)
        afr[kt] = cvt8(*(const float4*)(asrc + kt * 32), *(const float4*)(asrc + kt * 32 + 4));

    // B[k=d][n=W-row]: n = lane&15
    const float* wsrc = W + (size_t)(ntile * 16 + n) * KD + quad * 8;
    float4v acc = {0.f, 0.f, 0.f, 0.f};
    #pragma unroll
    for (int kt = 0; kt < 4; ++kt) {
        short8 bfr = cvt8(*(const float4*)(wsrc + kt * 32), *(const float4*)(wsrc + kt * 32 + 4));
        acc = __builtin_amdgcn_mfma_f32_16x16x32_bf16(afr[kt], bfr, acc, 0, 0, 0);
    }
    // D: col = lane&15 (= W row-in-tile), row = quad*4+r (= arg-in-tile)
    #pragma unroll
    for (int r = 0; r < 4; ++r)
        Qp[(size_t)(mtile * 16 + quad * 4 + r) * DM + ntile * 16 + n] = bf16_of(acc[r]);

    // qb: only one n-group per m-tile computes it
    if ((blockIdx.x & 7) == 0) {
        __shared__ float red[16][17];
        const int al = t >> 4, seg = t & 15;
        const float* qrow = arg + (size_t)(mtile * 16 + al) * KD + seg * 8;
        float p = 0.f;
        #pragma unroll
        for (int j = 0; j < 8; ++j) p += qrow[j] * b[seg * 8 + j];
        red[al][seg] = p;
        __syncthreads();
        if (t < 16) {
            float ssum = 0.f;
            #pragma unroll
            for (int j = 0; j < 16; ++j) ssum += red[t][j];
            qb[mtile * 16 + t] = ssum;
        }
    }
}

// grid 1024 = 16 states x 64 chunks of 16 ctx rows. 4 waves split K=512 (128 each).
// ctx is staged through LDS with COALESCED float4 loads (cvt to bf16 at staging);
// B-fragments then come from LDS as short8 (pad +8 shorts -> 2-way alias, free).
__global__ __launch_bounds__(256, 3) void main_kernel(
    const float* __restrict__ ctx, const short* __restrict__ Qp,
    const float* __restrict__ qb, float* __restrict__ out)
{
    __shared__ __align__(16) short Qpl[32][520];   // 33280 B
    __shared__ __align__(16) short Cxl[16][520];   // 16640 B  (total 49920 -> 3 blocks/CU)

    const int t = threadIdx.x, lane = t & 63, wave = t >> 6;
    const int s = blockIdx.x >> 6;
    const int chunk = blockIdx.x & 63;

    // stage Qp_s (32x512 bf16 = 32 KB): 2048 16B-units, coalesced
    const short* qsrc = Qp + (size_t)s * 32 * DM;
    #pragma unroll
    for (int i = 0; i < 8; ++i) {
        const int u = i * 256 + t;
        const int row = u >> 6, c = u & 63;
        *(float4*)&Qpl[row][c * 8] = *(const float4*)(qsrc + (size_t)row * DM + c * 8);
    }
    // stage ctx chunk (16x512 fp32 -> bf16): 1024 8-float units, coalesced float4 pairs
    const float* csrc = ctx + (size_t)(s * CTX_PER + chunk * 16) * DM;
    #pragma unroll
    for (int i = 0; i < 4; ++i) {
        const int u = i * 256 + t;
        const int row = u >> 6, c8 = u & 63;
        const float4 lo = *(const float4*)(csrc + (size_t)row * DM + c8 * 8);
        const float4 hi = *(const float4*)(csrc + (size_t)row * DM + c8 * 8 + 4);
        *(short8*)&Cxl[row][c8 * 8] = cvt8(lo, hi);
    }
    __syncthreads();

    const int n = lane & 15, quad = lane >> 4;
    const int k0 = wave * 128;                      // this wave's K-slice

    float4v acc0 = {0.f, 0.f, 0.f, 0.f};
    float4v acc1 = {0.f, 0.f, 0.f, 0.f};
    #pragma unroll
    for (int kt = 0; kt < 4; ++kt) {
        // B[k][n=ctx row]: bfr[j] = ctx[n][k0+kt*32+quad*8+j]
        short8 bfr = *(const short8*)&Cxl[n][k0 + kt * 32 + quad * 8];
        short8 a0  = *(const short8*)&Qpl[n][k0 + kt * 32 + quad * 8];
        short8 a1  = *(const short8*)&Qpl[16 + n][k0 + kt * 32 + quad * 8];
        acc0 = __builtin_amdgcn_mfma_f32_16x16x32_bf16(a0, bfr, acc0, 0, 0, 0);
        acc1 = __builtin_amdgcn_mfma_f32_16x16x32_bf16(a1, bfr, acc1, 0, 0, 0);
    }

    __syncthreads();                                // all waves done with LDS tiles
    float* Sp = (float*)&Qpl[0][0];                 // overlay: [wave][32 args][16 cols]
    // D: col = lane&15 = ctx row-in-tile, row = quad*4+r = arg-in-tile
    #pragma unroll
    for (int r = 0; r < 4; ++r) {
        Sp[wave * 512 + (quad * 4 + r) * 16 + n]      = acc0[r];
        Sp[wave * 512 + (16 + quad * 4 + r) * 16 + n] = acc1[r];
    }
    __syncthreads();

    // reduce 4 wave-partials + qb, write logits + rows (float2)
    const int a = t >> 3, c2 = (t & 7) * 2;
    const int base = a * 16 + c2;
    float v0 = Sp[base]     + Sp[512 + base]     + Sp[1024 + base]     + Sp[1536 + base];
    float v1 = Sp[base + 1] + Sp[512 + base + 1] + Sp[1024 + base + 1] + Sp[1536 + base + 1];
    const int ga = s * ARGS_PER + a;
    const float qbv = qb[ga];
    const size_t off = (size_t)ga * CTX_PER + chunk * 16 + c2;
    *(float2*)(out + P_TOTAL + off) = make_float2(v0 + qbv, v1 + qbv);
    *(float2*)(out + off)           = make_float2((float)ga, (float)ga);
}

extern "C" void kernel_launch(void* const* d_in, const int* in_sizes, int n_in,
                              void* d_out, int out_size, void* d_ws, size_t ws_size,
                              hipStream_t stream)
{
    // setup_inputs order: bs, arg_ids, ctx_ids, arg_values, ctx_values, W, b
    const float* arg_values = (const float*)d_in[3];
    const float* ctx_values = (const float*)d_in[4];
    const float* W          = (const float*)d_in[5];
    const float* b          = (const float*)d_in[6];
    float* out = (float*)d_out;

    short* Qp = (short*)d_ws;
    float* qb = (float*)((char*)d_ws + (size_t)N_ARGS * DM * sizeof(short));

    qproj_kernel<<<256, 256, 0, stream>>>(arg_values, W, b, Qp, qb);
    main_kernel<<<BSZ * 64, 256, 0, stream>>>(ctx_values, Qp, qb, out);
}